// Round 1
// baseline (1005.045 us; speedup 1.0000x reference)
//
#include <hip/hip_runtime.h>
#include <hip/hip_bf16.h>

// BLSTM: B=1024, T=512, V=128, H=128, HH=64, gates=256 per direction.
// d_in order: x[1024*512] i32, lengths[1024] i32 (UNUSED by reference),
//   emb[128*128] f32, W_ih_f[256*128], W_hh_f[256*64], W_ih_b[256*128],
//   W_hh_b[256*64], W_fc[128*128], b_fc[128]
// d_out: [1024*128] f32
//
// ws layout: tab (2*128*256 f32 = 256KB) @ 0 ; hfin (2*1024*64 f32 = 512KB) @ 256KB

#define T_STEPS 512
#define BATCH   1024
#define VOCAB   128
#define HID     128
#define HH      64
#define NG      256   // 4*HH
#define BT      8     // batch elems per workgroup

__device__ __forceinline__ float sigmoid_f(float x) {
    return 1.0f / (1.0f + __expf(-x));
}
__device__ __forceinline__ float tanh_f(float x) {
    // tanh(x) = 1 - 2/(exp(2x)+1); saturates correctly for |x| large
    return 1.0f - 2.0f / (__expf(2.0f * x) + 1.0f);
}

// ---------------- Kernel 1: input-projection tables ----------------
// tab[d][v][g] = sum_k emb[v][k] * W_ih_d[g][k]
__global__ __launch_bounds__(256) void build_tab_kernel(
    const float* __restrict__ emb,
    const float* __restrict__ W_ih_f,
    const float* __restrict__ W_ih_b,
    float* __restrict__ tab)
{
    int v = blockIdx.x;      // 0..127
    int d = blockIdx.y;      // 0..1
    int g = threadIdx.x;     // 0..255
    const float* W = d ? W_ih_b : W_ih_f;
    const float4* e4 = (const float4*)(emb + v * HID);
    const float4* w4 = (const float4*)(W + g * HID);
    float acc = 0.0f;
#pragma unroll
    for (int k = 0; k < HID / 4; ++k) {
        float4 e = e4[k];
        float4 w = w4[k];
        acc += e.x * w.x + e.y * w.y + e.z * w.z + e.w * w.w;
    }
    tab[(d * VOCAB + v) * NG + g] = acc;
}

// ---------------- Kernel 2: the recurrence ----------------
// grid: (128, 2)  block: 512
// Each workgroup: direction blockIdx.y, batch elems [blockIdx.x*8, +8), all 512 steps.
// Dot phase: thread (g = tid&255, bh = tid>>8) computes gate g for 4 batch elems.
// Combine phase: thread (b = tid>>6, j = tid&63) owns c[b][j] in a register.
__global__ __launch_bounds__(512) void lstm_rec_kernel(
    const int* __restrict__ x,          // [1024][512]
    const float* __restrict__ W_hh_f,   // [256][64]
    const float* __restrict__ W_hh_b,
    const float* __restrict__ tab,      // [2][128][256]
    float* __restrict__ hfin)           // [2][1024][64]
{
    __shared__ float h_lds[BT][HH];       // 2 KB
    __shared__ float gates[BT][NG];       // 8 KB
    __shared__ int   xs[BT][T_STEPS];     // 16 KB

    const int tid    = threadIdx.x;
    const int dir    = blockIdx.y;
    const int b_base = blockIdx.x * BT;

    const float* Whh  = dir ? W_hh_b : W_hh_f;
    const float* tabD = tab + dir * VOCAB * NG;

    // Load x tile: 8 rows of 512 contiguous ints
    for (int i = tid; i < BT * T_STEPS; i += 512) {
        int bl = i >> 9;        // /512
        int t  = i & (T_STEPS - 1);
        xs[bl][t] = x[(b_base + bl) * T_STEPS + t];
    }

    // Each thread holds its W_hh row (64 f32) in registers
    const int g  = tid & 255;
    const int bh = tid >> 8;     // 0 or 1 -> batch half
    float Wrow[HH];
#pragma unroll
    for (int k = 0; k < HH; k += 4) {
        float4 w = *(const float4*)(Whh + g * HH + k);
        Wrow[k] = w.x; Wrow[k + 1] = w.y; Wrow[k + 2] = w.z; Wrow[k + 3] = w.w;
    }

    // init h = 0
    if (tid < BT * HH) ((float*)h_lds)[tid] = 0.0f;

    // combine-phase ownership (tid 0..511 <-> (b 0..7, j 0..63))
    const int cb = tid >> 6;
    const int cj = tid & 63;
    float c_reg = 0.0f;
    float h_out = 0.0f;

    __syncthreads();

    const int b0 = bh * 4;
    for (int s = 0; s < T_STEPS; ++s) {
        const int t = dir ? (T_STEPS - 1 - s) : s;

        // ---- phase A: gate pre-activations ----
        const int v0 = xs[b0 + 0][t];
        const int v1 = xs[b0 + 1][t];
        const int v2 = xs[b0 + 2][t];
        const int v3 = xs[b0 + 3][t];
        float acc0 = tabD[v0 * NG + g];
        float acc1 = tabD[v1 * NG + g];
        float acc2 = tabD[v2 * NG + g];
        float acc3 = tabD[v3 * NG + g];
#pragma unroll
        for (int k = 0; k < HH; k += 4) {
            float4 h0 = *(const float4*)&h_lds[b0 + 0][k];
            float4 h1 = *(const float4*)&h_lds[b0 + 1][k];
            float4 h2 = *(const float4*)&h_lds[b0 + 2][k];
            float4 h3 = *(const float4*)&h_lds[b0 + 3][k];
            float w0 = Wrow[k], w1 = Wrow[k + 1], w2 = Wrow[k + 2], w3 = Wrow[k + 3];
            acc0 += w0 * h0.x + w1 * h0.y + w2 * h0.z + w3 * h0.w;
            acc1 += w0 * h1.x + w1 * h1.y + w2 * h1.z + w3 * h1.w;
            acc2 += w0 * h2.x + w1 * h2.y + w2 * h2.z + w3 * h2.w;
            acc3 += w0 * h3.x + w1 * h3.y + w2 * h3.z + w3 * h3.w;
        }
        gates[b0 + 0][g] = acc0;
        gates[b0 + 1][g] = acc1;
        gates[b0 + 2][g] = acc2;
        gates[b0 + 3][g] = acc3;

        __syncthreads();

        // ---- phase B: nonlinearities + state update ----
        float ig = gates[cb][cj];
        float fg = gates[cb][64 + cj];
        float gg = gates[cb][128 + cj];
        float og = gates[cb][192 + cj];
        float c_new = sigmoid_f(fg) * c_reg + sigmoid_f(ig) * tanh_f(gg);
        h_out = sigmoid_f(og) * tanh_f(c_new);
        c_reg = c_new;
        h_lds[cb][cj] = h_out;

        __syncthreads();
    }

    // final hidden state
    hfin[(dir * BATCH + b_base + cb) * HH + cj] = h_out;
}

// ---------------- Kernel 3: final FC ----------------
// out[b][v] = sum_j hid[b][j] * W_fc[v][j] + b_fc[v], hid = concat(h_f, h_b)
__global__ __launch_bounds__(128) void fc_kernel(
    const float* __restrict__ hfin,     // [2][1024][64]
    const float* __restrict__ W_fc,     // [128][128]
    const float* __restrict__ b_fc,     // [128]
    float* __restrict__ out)            // [1024][128]
{
    int b = blockIdx.x;
    int v = threadIdx.x;   // 0..127
    __shared__ float hid[HID];
    if (v < HH) hid[v] = hfin[(0 * BATCH + b) * HH + v];
    else        hid[v] = hfin[(1 * BATCH + b) * HH + (v - HH)];
    __syncthreads();
    const float4* w4 = (const float4*)(W_fc + v * HID);
    const float4* h4 = (const float4*)hid;
    float acc = b_fc[v];
#pragma unroll
    for (int k = 0; k < HID / 4; ++k) {
        float4 w = w4[k];
        float4 h = h4[k];
        acc += w.x * h.x + w.y * h.y + w.z * h.z + w.w * h.w;
    }
    out[b * HID + v] = acc;
}

extern "C" void kernel_launch(void* const* d_in, const int* in_sizes, int n_in,
                              void* d_out, int out_size, void* d_ws, size_t ws_size,
                              hipStream_t stream) {
    const int*   x      = (const int*)d_in[0];
    // d_in[1] = lengths : unused by the reference
    const float* emb    = (const float*)d_in[2];
    const float* W_ih_f = (const float*)d_in[3];
    const float* W_hh_f = (const float*)d_in[4];
    const float* W_ih_b = (const float*)d_in[5];
    const float* W_hh_b = (const float*)d_in[6];
    const float* W_fc   = (const float*)d_in[7];
    const float* b_fc   = (const float*)d_in[8];
    float* out = (float*)d_out;

    float* tab  = (float*)d_ws;                       // 2*128*256 f32 = 256 KB
    float* hfin = tab + 2 * VOCAB * NG;               // 2*1024*64 f32 = 512 KB

    build_tab_kernel<<<dim3(VOCAB, 2), 256, 0, stream>>>(emb, W_ih_f, W_ih_b, tab);
    lstm_rec_kernel<<<dim3(BATCH / BT, 2), 512, 0, stream>>>(x, W_hh_f, W_hh_b, tab, hfin);
    fc_kernel<<<dim3(BATCH), 128, 0, stream>>>(hfin, W_fc, b_fc, out);
}

// Round 2
// 864.513 us; speedup vs baseline: 1.1626x; 1.1626x over previous
//
#include <hip/hip_runtime.h>
#include <hip/hip_bf16.h>

// BLSTM: B=1024, T=512, V=128, H=128, HH=64, gates=256 per direction.
// ws layout: tab (2*128*256 f32 = 256KB) @ 0 ; hfin (2*1024*64 f32 = 512KB) after

#define T_STEPS 512
#define BATCH   1024
#define VOCAB   128
#define HID     128
#define HH      64
#define NG      256   // 4*HH
#define BT      8     // batch elems per workgroup

typedef float f2 __attribute__((ext_vector_type(2)));

__device__ __forceinline__ float sigmoid_f(float x) {
    return 1.0f / (1.0f + __expf(-x));
}
__device__ __forceinline__ float tanh_f(float x) {
    return 1.0f - 2.0f / (__expf(2.0f * x) + 1.0f);
}

// ---------------- Kernel 1: input-projection tables ----------------
// tab[d][v][g] = sum_k emb[v][k] * W_ih_d[g][k]
__global__ __launch_bounds__(256) void build_tab_kernel(
    const float* __restrict__ emb,
    const float* __restrict__ W_ih_f,
    const float* __restrict__ W_ih_b,
    float* __restrict__ tab)
{
    int v = blockIdx.x;      // 0..127
    int d = blockIdx.y;      // 0..1
    int g = threadIdx.x;     // 0..255
    const float* W = d ? W_ih_b : W_ih_f;
    const float4* e4 = (const float4*)(emb + v * HID);
    const float4* w4 = (const float4*)(W + g * HID);
    float acc = 0.0f;
#pragma unroll
    for (int k = 0; k < HID / 4; ++k) {
        float4 e = e4[k];
        float4 w = w4[k];
        acc += e.x * w.x + e.y * w.y + e.z * w.z + e.w * w.w;
    }
    tab[(d * VOCAB + v) * NG + g] = acc;
}

// ---------------- Kernel 2: the recurrence ----------------
// grid: (128, 2)  block: 512.  __launch_bounds__(512,2): 2 waves/SIMD resident
// -> VGPR cap 256, so the 64-float W_hh row stays register-resident (R1: VGPR=60
//    meant the compiler was re-loading weights every step -> 3.6x VALU cycles).
__global__ __launch_bounds__(512, 2) void lstm_rec_kernel(
    const int* __restrict__ x,          // [1024][512]
    const float* __restrict__ W_hh_f,   // [256][64]
    const float* __restrict__ W_hh_b,
    const float* __restrict__ tab,      // [2][128][256]
    float* __restrict__ hfin)           // [2][1024][64]
{
    __shared__ float h_lds[BT][HH];       // 2 KB
    __shared__ float gates[BT][NG];       // 8 KB
    __shared__ int   xs[BT][T_STEPS];     // 16 KB

    const int tid    = threadIdx.x;
    const int dir    = blockIdx.y;
    const int b_base = blockIdx.x * BT;

    const float* Whh  = dir ? W_hh_b : W_hh_f;
    const float* tabD = tab + dir * VOCAB * NG;

    // Load x tile: 8 rows of 512 contiguous ints
    for (int i = tid; i < BT * T_STEPS; i += 512) {
        int bl = i >> 9;
        int t  = i & (T_STEPS - 1);
        xs[bl][t] = x[(b_base + bl) * T_STEPS + t];
    }

    // Each thread holds its W_hh row (64 f32 = 32 x f2) in registers
    const int g  = tid & 255;
    const int bh = tid >> 8;     // batch half
    const int b0 = bh * 4;
    f2 W[32];
    {
        const f2* wsrc = (const f2*)(Whh + g * HH);
#pragma unroll
        for (int k = 0; k < 32; ++k) W[k] = wsrc[k];
    }

    // init h = 0
    if (tid < BT * HH) ((float*)h_lds)[tid] = 0.0f;

    // combine-phase ownership (tid <-> (b, j))
    const int cb = tid >> 6;
    const int cj = tid & 63;
    float c_reg = 0.0f;
    float h_out = 0.0f;

    __syncthreads();   // xs + h_lds visible

    // software-pipelined tab gather: prefetch step 0
    const int t0 = dir ? (T_STEPS - 1) : 0;
    float n0 = tabD[xs[b0 + 0][t0] * NG + g];
    float n1 = tabD[xs[b0 + 1][t0] * NG + g];
    float n2 = tabD[xs[b0 + 2][t0] * NG + g];
    float n3 = tabD[xs[b0 + 3][t0] * NG + g];

    for (int s = 0; s < T_STEPS; ++s) {
        // ---- phase A: gate pre-activations ----
        f2 a0 = {n0, 0.0f}, a0b = {0.0f, 0.0f};
        f2 a1 = {n1, 0.0f}, a1b = {0.0f, 0.0f};
        f2 a2 = {n2, 0.0f}, a2b = {0.0f, 0.0f};
        f2 a3 = {n3, 0.0f}, a3b = {0.0f, 0.0f};

        // prefetch next step's input projection (overlaps compute + barrier)
        if (s + 1 < T_STEPS) {
            const int tn = dir ? (T_STEPS - 2 - s) : (s + 1);
            n0 = tabD[xs[b0 + 0][tn] * NG + g];
            n1 = tabD[xs[b0 + 1][tn] * NG + g];
            n2 = tabD[xs[b0 + 2][tn] * NG + g];
            n3 = tabD[xs[b0 + 3][tn] * NG + g];
        }

#pragma unroll
        for (int k = 0; k < 16; ++k) {
            float4 h0 = *(const float4*)&h_lds[b0 + 0][k * 4];
            float4 h1 = *(const float4*)&h_lds[b0 + 1][k * 4];
            float4 h2 = *(const float4*)&h_lds[b0 + 2][k * 4];
            float4 h3 = *(const float4*)&h_lds[b0 + 3][k * 4];
            f2 w0 = W[2 * k], w1 = W[2 * k + 1];
            a0  += w0 * f2{h0.x, h0.y};
            a0b += w1 * f2{h0.z, h0.w};
            a1  += w0 * f2{h1.x, h1.y};
            a1b += w1 * f2{h1.z, h1.w};
            a2  += w0 * f2{h2.x, h2.y};
            a2b += w1 * f2{h2.z, h2.w};
            a3  += w0 * f2{h3.x, h3.y};
            a3b += w1 * f2{h3.z, h3.w};
        }
        gates[b0 + 0][g] = a0.x + a0.y + a0b.x + a0b.y;
        gates[b0 + 1][g] = a1.x + a1.y + a1b.x + a1b.y;
        gates[b0 + 2][g] = a2.x + a2.y + a2b.x + a2b.y;
        gates[b0 + 3][g] = a3.x + a3.y + a3b.x + a3b.y;

        __syncthreads();

        // ---- phase B: nonlinearities + state update ----
        float ig = gates[cb][cj];
        float fg = gates[cb][64 + cj];
        float gg = gates[cb][128 + cj];
        float og = gates[cb][192 + cj];
        float c_new = sigmoid_f(fg) * c_reg + sigmoid_f(ig) * tanh_f(gg);
        h_out = sigmoid_f(og) * tanh_f(c_new);
        c_reg = c_new;
        h_lds[cb][cj] = h_out;

        __syncthreads();
    }

    hfin[(dir * BATCH + b_base + cb) * HH + cj] = h_out;
}

// ---------------- Kernel 3: final FC ----------------
__global__ __launch_bounds__(128) void fc_kernel(
    const float* __restrict__ hfin,     // [2][1024][64]
    const float* __restrict__ W_fc,     // [128][128]
    const float* __restrict__ b_fc,     // [128]
    float* __restrict__ out)            // [1024][128]
{
    int b = blockIdx.x;
    int v = threadIdx.x;   // 0..127
    __shared__ float hid[HID];
    if (v < HH) hid[v] = hfin[(0 * BATCH + b) * HH + v];
    else        hid[v] = hfin[(1 * BATCH + b) * HH + (v - HH)];
    __syncthreads();
    const float4* w4 = (const float4*)(W_fc + v * HID);
    const float4* h4 = (const float4*)hid;
    float acc = b_fc[v];
#pragma unroll
    for (int k = 0; k < HID / 4; ++k) {
        float4 w = w4[k];
        float4 h = h4[k];
        acc += w.x * h.x + w.y * h.y + w.z * h.z + w.w * h.w;
    }
    out[b * HID + v] = acc;
}

extern "C" void kernel_launch(void* const* d_in, const int* in_sizes, int n_in,
                              void* d_out, int out_size, void* d_ws, size_t ws_size,
                              hipStream_t stream) {
    const int*   x      = (const int*)d_in[0];
    // d_in[1] = lengths : unused by the reference
    const float* emb    = (const float*)d_in[2];
    const float* W_ih_f = (const float*)d_in[3];
    const float* W_hh_f = (const float*)d_in[4];
    const float* W_ih_b = (const float*)d_in[5];
    const float* W_hh_b = (const float*)d_in[6];
    const float* W_fc   = (const float*)d_in[7];
    const float* b_fc   = (const float*)d_in[8];
    float* out = (float*)d_out;

    float* tab  = (float*)d_ws;                       // 2*128*256 f32 = 256 KB
    float* hfin = tab + 2 * VOCAB * NG;               // 2*1024*64 f32 = 512 KB

    build_tab_kernel<<<dim3(VOCAB, 2), 256, 0, stream>>>(emb, W_ih_f, W_ih_b, tab);
    lstm_rec_kernel<<<dim3(BATCH / BT, 2), 512, 0, stream>>>(x, W_hh_f, W_hh_b, tab, hfin);
    fc_kernel<<<dim3(BATCH), 128, 0, stream>>>(hfin, W_fc, b_fc, out);
}

// Round 3
// 538.375 us; speedup vs baseline: 1.8668x; 1.6058x over previous
//
#include <hip/hip_runtime.h>
#include <hip/hip_bf16.h>

// BLSTM: B=1024, T=512, V=128, H=128, HH=64, gates=256/dir.
// R3: recurrence matmul moved to MFMA bf16x3 (W=Whi+Wlo, h=hhi+hlo, 3 terms).
// Per block: 8 batch rows (padded to one 16-row M-tile), all 256 gates, 512 thr.
// B-fragments (weights) persistent in VGPRs (8 frags x 4 VGPR = 32), loaded once.
// ws: tab f32[2][128][256] @0 (256KB) ; whh_hi u16[2][256][64] (64KB) ;
//     whh_lo (64KB) ; hfin f32[2][1024][64] (512KB). total ~896KB.

#define T_STEPS 512
#define BATCH   1024
#define VOCAB   128
#define HID     128
#define HH      64
#define NG      256
#define MB      8      // real batch rows per block

typedef __attribute__((ext_vector_type(8))) short bf16x8;
typedef __attribute__((ext_vector_type(4))) float f32x4;
typedef unsigned int  u32;
typedef unsigned short u16;

__device__ __forceinline__ float sigmoid_f(float x) {
    return 1.0f / (1.0f + __expf(-x));
}
__device__ __forceinline__ float tanh_f(float x) {
    return 1.0f - 2.0f / (__expf(2.0f * x) + 1.0f);
}
// round-to-nearest-even f32 -> bf16 bits
__device__ __forceinline__ u16 f2bf(float f) {
    u32 u = __builtin_bit_cast(u32, f);
    u += 0x7FFFu + ((u >> 16) & 1u);
    return (u16)(u >> 16);
}
__device__ __forceinline__ float bf2f(u16 b) {
    return __builtin_bit_cast(float, ((u32)b) << 16);
}

// ---------------- Kernel 1: input-projection tables (f32, exact) ----------------
__global__ __launch_bounds__(256) void build_tab_kernel(
    const float* __restrict__ emb,
    const float* __restrict__ W_ih_f,
    const float* __restrict__ W_ih_b,
    float* __restrict__ tab)
{
    int v = blockIdx.x, d = blockIdx.y, g = threadIdx.x;
    const float* W = d ? W_ih_b : W_ih_f;
    const float4* e4 = (const float4*)(emb + v * HID);
    const float4* w4 = (const float4*)(W + g * HID);
    float acc = 0.0f;
#pragma unroll
    for (int k = 0; k < HID / 4; ++k) {
        float4 e = e4[k]; float4 w = w4[k];
        acc += e.x * w.x + e.y * w.y + e.z * w.z + e.w * w.w;
    }
    tab[(d * VOCAB + v) * NG + g] = acc;
}

// ---------------- Kernel 1b: split W_hh into bf16 hi/lo ----------------
__global__ __launch_bounds__(64) void split_whh_kernel(
    const float* __restrict__ W_hh_f,
    const float* __restrict__ W_hh_b,
    u16* __restrict__ whh_hi,
    u16* __restrict__ whh_lo)
{
    int g = blockIdx.x;           // 0..255
    int d = blockIdx.y;           // 0..1
    int k = threadIdx.x;          // 0..63
    const float* W = d ? W_hh_b : W_hh_f;
    float w = W[g * HH + k];
    u16 hb = f2bf(w);
    u16 lb = f2bf(w - bf2f(hb));
    whh_hi[(d * NG + g) * HH + k] = hb;
    whh_lo[(d * NG + g) * HH + k] = lb;
}

// ---------------- Kernel 2: MFMA recurrence ----------------
// grid (128, 2), block 512 (8 waves). Wave w owns N-tiles [w*16, w*16+128).
// M-tile rows 0..7 real, 8..15 dummy (h kept 0; xs mirrored via m&7).
__global__ __launch_bounds__(512, 2) void lstm_rec_kernel(
    const int*  __restrict__ x,        // [1024][512]
    const u16*  __restrict__ whh_hi,   // [2][256][64] bf16 bits
    const u16*  __restrict__ whh_lo,
    const float* __restrict__ tab,     // [2][128][256]
    float* __restrict__ hfin)          // [2][1024][64]
{
    __shared__ int   xs[T_STEPS][MB];     // [t][m] transposed, 16KB
    __shared__ u16   h_hi[16][72];        // pad 64->72: row stride 144B breaks
    __shared__ u16   h_lo[16][72];        //  the 128B power-of-2 bank stride
    __shared__ float gates[MB][NG];       // 8KB

    const int tid  = threadIdx.x;
    const int lane = tid & 63;
    const int wave = tid >> 6;            // 0..7
    const int quad = lane >> 4;           // 0..3
    const int mrow = lane & 15;           // A-row / C-col index
    const int dir    = blockIdx.y;
    const int b_base = blockIdx.x * MB;

    // stage x transposed: xs[t][m]
    for (int i = tid; i < MB * T_STEPS; i += 512) {
        int m = i >> 9, t = i & (T_STEPS - 1);
        xs[t][m] = x[(b_base + m) * T_STEPS + t];
    }
    // zero h (all 16 rows incl. dummy)
    for (int i = tid; i < 16 * 72; i += 512) {
        ((u16*)h_hi)[i] = 0; ((u16*)h_lo)[i] = 0;
    }

    // persistent B-fragments: B[k][n] = Whh[n][k]; lane holds row n0+mrow,
    // k = kc*32 + quad*8 + j (j=0..7 contiguous) -> one 16B load per frag.
    const u16* WH = whh_hi + dir * NG * HH;
    const u16* WL = whh_lo + dir * NG * HH;
    const int n0 = wave * 16;
    bf16x8 Bh[2][2], Bl[2][2];            // [tile][kc]
#pragma unroll
    for (int tile = 0; tile < 2; ++tile) {
        int row = n0 + tile * 128 + mrow;
#pragma unroll
        for (int kc = 0; kc < 2; ++kc) {
            int kidx = kc * 32 + quad * 8;
            Bh[tile][kc] = *(const bf16x8*)(WH + row * HH + kidx);
            Bl[tile][kc] = *(const bf16x8*)(WL + row * HH + kidx);
        }
    }

    const float* tabD = tab + dir * VOCAB * NG;
    const int col0 = n0 + mrow;           // C cols for tile 0 / tile 1 (+128)

    float c_reg = 0.0f, h_out = 0.0f;

    __syncthreads();

    // prefetch accumulator init (tab gather) for first step
    float init0[4], init1[4];
    {
        const int t0 = dir ? (T_STEPS - 1) : 0;
#pragma unroll
        for (int r = 0; r < 4; ++r) {
            int m = (quad * 4 + r) & 7;
            int v = xs[t0][m];
            init0[r] = tabD[v * NG + col0];
            init1[r] = tabD[v * NG + col0 + 128];
        }
    }

    for (int s = 0; s < T_STEPS; ++s) {
        // ---- phase A: gates = tab + Hhi*Whi + Hlo*Whi + Hhi*Wlo ----
        bf16x8 Ah[2], Al[2];
#pragma unroll
        for (int kc = 0; kc < 2; ++kc) {
            int kb = kc * 32 + quad * 8;
            Ah[kc] = *(const bf16x8*)&h_hi[mrow][kb];
            Al[kc] = *(const bf16x8*)&h_lo[mrow][kb];
        }
        f32x4 acc0 = {init0[0], init0[1], init0[2], init0[3]};
        f32x4 acc1 = {init1[0], init1[1], init1[2], init1[3]};
        acc0 = __builtin_amdgcn_mfma_f32_16x16x32_bf16(Ah[0], Bh[0][0], acc0, 0, 0, 0);
        acc1 = __builtin_amdgcn_mfma_f32_16x16x32_bf16(Ah[0], Bh[1][0], acc1, 0, 0, 0);
        acc0 = __builtin_amdgcn_mfma_f32_16x16x32_bf16(Ah[1], Bh[0][1], acc0, 0, 0, 0);
        acc1 = __builtin_amdgcn_mfma_f32_16x16x32_bf16(Ah[1], Bh[1][1], acc1, 0, 0, 0);
        acc0 = __builtin_amdgcn_mfma_f32_16x16x32_bf16(Al[0], Bh[0][0], acc0, 0, 0, 0);
        acc1 = __builtin_amdgcn_mfma_f32_16x16x32_bf16(Al[0], Bh[1][0], acc1, 0, 0, 0);
        acc0 = __builtin_amdgcn_mfma_f32_16x16x32_bf16(Al[1], Bh[0][1], acc0, 0, 0, 0);
        acc1 = __builtin_amdgcn_mfma_f32_16x16x32_bf16(Al[1], Bh[1][1], acc1, 0, 0, 0);
        acc0 = __builtin_amdgcn_mfma_f32_16x16x32_bf16(Ah[0], Bl[0][0], acc0, 0, 0, 0);
        acc1 = __builtin_amdgcn_mfma_f32_16x16x32_bf16(Ah[0], Bl[1][0], acc1, 0, 0, 0);
        acc0 = __builtin_amdgcn_mfma_f32_16x16x32_bf16(Ah[1], Bl[0][1], acc0, 0, 0, 0);
        acc1 = __builtin_amdgcn_mfma_f32_16x16x32_bf16(Ah[1], Bl[1][1], acc1, 0, 0, 0);

        // store gates: C layout col=lane&15, row=quad*4+r; only rows 0..7 real
        if (quad < 2) {
#pragma unroll
            for (int r = 0; r < 4; ++r) {
                gates[quad * 4 + r][col0]       = acc0[r];
                gates[quad * 4 + r][col0 + 128] = acc1[r];
            }
        }

        // prefetch next step's tab init (latency hidden by barrier + phase B)
        if (s + 1 < T_STEPS) {
            const int tn = dir ? (T_STEPS - 2 - s) : (s + 1);
#pragma unroll
            for (int r = 0; r < 4; ++r) {
                int m = (quad * 4 + r) & 7;
                int v = xs[tn][m];
                init0[r] = tabD[v * NG + col0];
                init1[r] = tabD[v * NG + col0 + 128];
            }
        }

        __syncthreads();

        // ---- phase B: tid <-> (b=wave, j=lane) ----
        float ig = gates[wave][lane];
        float fg = gates[wave][64 + lane];
        float gg = gates[wave][128 + lane];
        float og = gates[wave][192 + lane];
        float c_new = sigmoid_f(fg) * c_reg + sigmoid_f(ig) * tanh_f(gg);
        h_out = sigmoid_f(og) * tanh_f(c_new);
        c_reg = c_new;
        u16 hb = f2bf(h_out);
        u16 lb = f2bf(h_out - bf2f(hb));
        h_hi[wave][lane] = hb;
        h_lo[wave][lane] = lb;

        __syncthreads();
    }

    hfin[(dir * BATCH + b_base + wave) * HH + lane] = h_out;
}

// ---------------- Kernel 3: final FC ----------------
__global__ __launch_bounds__(128) void fc_kernel(
    const float* __restrict__ hfin,
    const float* __restrict__ W_fc,
    const float* __restrict__ b_fc,
    float* __restrict__ out)
{
    int b = blockIdx.x;
    int v = threadIdx.x;
    __shared__ float hid[HID];
    if (v < HH) hid[v] = hfin[(0 * BATCH + b) * HH + v];
    else        hid[v] = hfin[(1 * BATCH + b) * HH + (v - HH)];
    __syncthreads();
    const float4* w4 = (const float4*)(W_fc + v * HID);
    const float4* h4 = (const float4*)hid;
    float acc = b_fc[v];
#pragma unroll
    for (int k = 0; k < HID / 4; ++k) {
        float4 w = w4[k]; float4 h = h4[k];
        acc += w.x * h.x + w.y * h.y + w.z * h.z + w.w * h.w;
    }
    out[b * HID + v] = acc;
}

extern "C" void kernel_launch(void* const* d_in, const int* in_sizes, int n_in,
                              void* d_out, int out_size, void* d_ws, size_t ws_size,
                              hipStream_t stream) {
    const int*   x      = (const int*)d_in[0];
    // d_in[1] = lengths : unused by the reference
    const float* emb    = (const float*)d_in[2];
    const float* W_ih_f = (const float*)d_in[3];
    const float* W_hh_f = (const float*)d_in[4];
    const float* W_ih_b = (const float*)d_in[5];
    const float* W_hh_b = (const float*)d_in[6];
    const float* W_fc   = (const float*)d_in[7];
    const float* b_fc   = (const float*)d_in[8];
    float* out = (float*)d_out;

    float* tab    = (float*)d_ws;                         // 65536 f32
    u16*   whh_hi = (u16*)(tab + 2 * VOCAB * NG);         // 32768 u16
    u16*   whh_lo = whh_hi + 2 * NG * HH;                 // 32768 u16
    float* hfin   = (float*)(whh_lo + 2 * NG * HH);       // 131072 f32

    build_tab_kernel<<<dim3(VOCAB, 2), 256, 0, stream>>>(emb, W_ih_f, W_ih_b, tab);
    split_whh_kernel<<<dim3(NG, 2), 64, 0, stream>>>(W_hh_f, W_hh_b, whh_hi, whh_lo);
    lstm_rec_kernel<<<dim3(BATCH / MB, 2), 512, 0, stream>>>(x, whh_hi, whh_lo, tab, hfin);
    fc_kernel<<<dim3(BATCH), 128, 0, stream>>>(hfin, W_fc, b_fc, out);
}